// Round 3
// baseline (153.167 us; speedup 1.0000x reference)
//
#include <hip/hip_runtime.h>

// NestedFormula: DEPTH=4, V=4, B=131072.
// Level node counts: n1=125, n2=25, n3=5, n4=1; lam0 has 125 entries.
// Depth-first evaluation, E=4 batch elements per thread:
//  - amortizes the ~2125 wave-uniform scalar param loads 4x
//  - gives 4-way ILP so v_exp_f32 (8 cyc/wave) latency is hidden and the
//    compiler can pack independent fp32 FMAs into v_pk_fma_f32
// Raw v_exp_f32 / v_log_f32 via builtins (OCML exp2f/log2f add denormal
// fixup code we never need: x in [0.5,1.5], powers ~N(0,0.25)).

#define VV 4
#define E  4

__global__ __launch_bounds__(256) void nested_formula_kernel(
    const float4* __restrict__ x,      // (B, 4) as float4
    const float*  __restrict__ lam0,   // (125,)
    const float*  __restrict__ lam1,   // (125,4)
    const float*  __restrict__ pow1,   // (125,4)
    const float*  __restrict__ lam2,   // (25,4)
    const float*  __restrict__ pow2,   // (25,4)
    const float*  __restrict__ lam3,   // (5,4)
    const float*  __restrict__ pow3,   // (5,4)
    const float*  __restrict__ lam4,   // (1,4)
    const float*  __restrict__ pow4,   // (1,4)
    float* __restrict__ out,           // (B,)
    int B)
{
    const int NT = gridDim.x * blockDim.x;
    const int t  = blockIdx.x * blockDim.x + threadIdx.x;

    float lx[E][VV];
#pragma unroll
    for (int e = 0; e < E; ++e) {
        int b = t + e * NT;
        float4 xv = (b < B) ? x[b] : make_float4(1.f, 1.f, 1.f, 1.f);
        lx[e][0] = __builtin_amdgcn_logf(xv.x);
        lx[e][1] = __builtin_amdgcn_logf(xv.y);
        lx[e][2] = __builtin_amdgcn_logf(xv.z);
        lx[e][3] = __builtin_amdgcn_logf(xv.w);
    }

    float acc4[E], last4[E];
#pragma unroll
    for (int e = 0; e < E; ++e) { acc4[e] = 0.f; last4[e] = 0.f; }

#pragma unroll
    for (int c3 = 0; c3 < VV + 1; ++c3) {
        float acc3[E], last3[E];
#pragma unroll
        for (int e = 0; e < E; ++e) { acc3[e] = 0.f; last3[e] = 0.f; }

#pragma unroll
        for (int c2 = 0; c2 < VV + 1; ++c2) {
            const int n2 = c3 * (VV + 1) + c2;     // 0..24
            float acc2[E], last2[E];
#pragma unroll
            for (int e = 0; e < E; ++e) { acc2[e] = 0.f; last2[e] = 0.f; }

#pragma unroll
            for (int c1 = 0; c1 < VV + 1; ++c1) {
                const int n1 = n2 * (VV + 1) + c1; // 0..124
                float f1[E];
                const float l0 = lam0[n1];
#pragma unroll
                for (int e = 0; e < E; ++e) f1[e] = l0;
#pragma unroll
                for (int v = 0; v < VV; ++v) {
                    const float p = pow1[n1 * VV + v];
                    const float l = lam1[n1 * VV + v];
#pragma unroll
                    for (int e = 0; e < E; ++e)
                        f1[e] = fmaf(l, __builtin_amdgcn_exp2f(p * lx[e][v]), f1[e]);
                }
                if (c1 < VV) {
                    const float p = pow2[n2 * VV + c1];
                    const float l = lam2[n2 * VV + c1];
#pragma unroll
                    for (int e = 0; e < E; ++e)
                        acc2[e] = fmaf(l * __builtin_amdgcn_exp2f(p * lx[e][c1]), f1[e], acc2[e]);
                } else {
#pragma unroll
                    for (int e = 0; e < E; ++e) last2[e] = f1[e];
                }
            }

            if (c2 < VV) {
                const float p = pow3[c3 * VV + c2];
                const float l = lam3[c3 * VV + c2];
#pragma unroll
                for (int e = 0; e < E; ++e)
                    acc3[e] = fmaf(l * __builtin_amdgcn_exp2f(p * lx[e][c2]),
                                   acc2[e] + last2[e], acc3[e]);
            } else {
#pragma unroll
                for (int e = 0; e < E; ++e) last3[e] = acc2[e] + last2[e];
            }
        }

        if (c3 < VV) {
            const float p = pow4[c3];
            const float l = lam4[c3];
#pragma unroll
            for (int e = 0; e < E; ++e)
                acc4[e] = fmaf(l * __builtin_amdgcn_exp2f(p * lx[e][c3]),
                               acc3[e] + last3[e], acc4[e]);
        } else {
#pragma unroll
            for (int e = 0; e < E; ++e) last4[e] = acc3[e] + last3[e];
        }
    }

#pragma unroll
    for (int e = 0; e < E; ++e) {
        int b = t + e * NT;
        if (b < B) out[b] = acc4[e] + last4[e];
    }
}

extern "C" void kernel_launch(void* const* d_in, const int* in_sizes, int n_in,
                              void* d_out, int out_size, void* d_ws, size_t ws_size,
                              hipStream_t stream) {
    const float4* x    = (const float4*)d_in[0];
    const float*  lam0 = (const float*)d_in[1];
    const float*  lam1 = (const float*)d_in[2];
    const float*  pow1 = (const float*)d_in[3];
    const float*  lam2 = (const float*)d_in[4];
    const float*  pow2 = (const float*)d_in[5];
    const float*  lam3 = (const float*)d_in[6];
    const float*  pow3 = (const float*)d_in[7];
    const float*  lam4 = (const float*)d_in[8];
    const float*  pow4 = (const float*)d_in[9];
    float* out = (float*)d_out;

    int B = in_sizes[0] / 4;  // x is (B, 4)
    int block = 256;
    int grid = (B + block * E - 1) / (block * E);   // 128 blocks at B=131072
    nested_formula_kernel<<<grid, block, 0, stream>>>(
        x, lam0, lam1, pow1, lam2, pow2, lam3, pow3, lam4, pow4, out, B);
}

// Round 4
// 88.822 us; speedup vs baseline: 1.7244x; 1.7244x over previous
//
#include <hip/hip_runtime.h>

// NestedFormula: DEPTH=4, V=4, B=131072. n1=125, n2=25, n3=5, n4=1.
//
// 4-way tree split per batch element across blockIdx.y = r (wave-uniform,
// so params stay scalar-loaded and there is NO divergence):
//   thread r: A_r = lam4[r]*x_r^pow4[r] * f3(r)                (125 exps)
//           + B_r = lam3[4,r]*x_r^pow3[4,r] * f2(20+r)         ( 25 exps)
//           + C_r = lam2[24,r]*x_r^pow2[24,r] * f1(120+r)      (  5 exps)
//           + (r==0 ? f1(124) : 0)                             (  4 exps)
//   out[b] = sum_r partial_r   via fp32 atomic into zeroed d_out.
// This yields 8192 waves (8/SIMD, max occupancy) vs the 2048-wave cap of
// one-thread-per-element, and shrinks the unrolled body ~4x (I-cache fits).

#define VV 4

__device__ __forceinline__ float f1_eval(int n1, const float lx[VV],
    const float* __restrict__ lam0, const float* __restrict__ lam1,
    const float* __restrict__ pow1)
{
    float f = lam0[n1];
#pragma unroll
    for (int v = 0; v < VV; ++v)
        f = fmaf(lam1[n1 * VV + v],
                 __builtin_amdgcn_exp2f(pow1[n1 * VV + v] * lx[v]), f);
    return f;
}

__device__ __forceinline__ float f2_eval(int n2, const float lx[VV],
    const float* __restrict__ lam0, const float* __restrict__ lam1,
    const float* __restrict__ pow1, const float* __restrict__ lam2,
    const float* __restrict__ pow2)
{
    float acc = 0.f;
#pragma unroll
    for (int c1 = 0; c1 < VV; ++c1) {
        float f1 = f1_eval(n2 * (VV + 1) + c1, lx, lam0, lam1, pow1);
        acc = fmaf(lam2[n2 * VV + c1] *
                       __builtin_amdgcn_exp2f(pow2[n2 * VV + c1] * lx[c1]),
                   f1, acc);
    }
    return acc + f1_eval(n2 * (VV + 1) + VV, lx, lam0, lam1, pow1);
}

__device__ __forceinline__ float f3_eval(int n3, const float lx[VV],
    const float* __restrict__ lam0, const float* __restrict__ lam1,
    const float* __restrict__ pow1, const float* __restrict__ lam2,
    const float* __restrict__ pow2, const float* __restrict__ lam3,
    const float* __restrict__ pow3)
{
    float acc = 0.f;
#pragma unroll
    for (int c2 = 0; c2 < VV; ++c2) {
        float f2 = f2_eval(n3 * (VV + 1) + c2, lx, lam0, lam1, pow1, lam2, pow2);
        acc = fmaf(lam3[n3 * VV + c2] *
                       __builtin_amdgcn_exp2f(pow3[n3 * VV + c2] * lx[c2]),
                   f2, acc);
    }
    return acc + f2_eval(n3 * (VV + 1) + VV, lx, lam0, lam1, pow1, lam2, pow2);
}

__global__ __launch_bounds__(256) void nested_formula_r4(
    const float4* __restrict__ x,      // (B, 4)
    const float*  __restrict__ lam0,   // (125,)
    const float*  __restrict__ lam1,   // (125,4)
    const float*  __restrict__ pow1,   // (125,4)
    const float*  __restrict__ lam2,   // (25,4)
    const float*  __restrict__ pow2,   // (25,4)
    const float*  __restrict__ lam3,   // (5,4)
    const float*  __restrict__ pow3,   // (5,4)
    const float*  __restrict__ lam4,   // (1,4)
    const float*  __restrict__ pow4,   // (1,4)
    float* __restrict__ out,           // (B,) pre-zeroed
    int B)
{
    const int r = blockIdx.y;                          // 0..3, wave-uniform
    const int b = blockIdx.x * blockDim.x + threadIdx.x;
    if (b >= B) return;

    float4 xv = x[b];
    float lx[VV] = { __builtin_amdgcn_logf(xv.x), __builtin_amdgcn_logf(xv.y),
                     __builtin_amdgcn_logf(xv.z), __builtin_amdgcn_logf(xv.w) };
    // lx[r] with uniform runtime r -> one-time cndmask select
    const float lxr = (r == 0) ? lx[0] : (r == 1) ? lx[1] : (r == 2) ? lx[2] : lx[3];

    // A_r: depth-3 subtree r, weighted by the depth-4 edge
    float f3 = f3_eval(r, lx, lam0, lam1, pow1, lam2, pow2, lam3, pow3);
    float partial = lam4[r] * __builtin_amdgcn_exp2f(pow4[r] * lxr) * f3;

    // B_r: depth-2 node (20+r) = child r of depth-3 node 4
    float f2 = f2_eval(4 * (VV + 1) + r, lx, lam0, lam1, pow1, lam2, pow2);
    partial = fmaf(lam3[4 * VV + r] * __builtin_amdgcn_exp2f(pow3[4 * VV + r] * lxr),
                   f2, partial);

    // C_r: depth-1 node (120+r) = child r of depth-2 node 24
    float f1 = f1_eval(24 * (VV + 1) + r, lx, lam0, lam1, pow1);
    partial = fmaf(lam2[24 * VV + r] * __builtin_amdgcn_exp2f(pow2[24 * VV + r] * lxr),
                   f1, partial);

    // last chain: f1(124) contributes raw (assign to r==0; wave-uniform branch)
    if (r == 0)
        partial += f1_eval(24 * (VV + 1) + VV, lx, lam0, lam1, pow1);

    unsafeAtomicAdd(&out[b], partial);
}

extern "C" void kernel_launch(void* const* d_in, const int* in_sizes, int n_in,
                              void* d_out, int out_size, void* d_ws, size_t ws_size,
                              hipStream_t stream) {
    const float4* x    = (const float4*)d_in[0];
    const float*  lam0 = (const float*)d_in[1];
    const float*  lam1 = (const float*)d_in[2];
    const float*  pow1 = (const float*)d_in[3];
    const float*  lam2 = (const float*)d_in[4];
    const float*  pow2 = (const float*)d_in[5];
    const float*  lam3 = (const float*)d_in[6];
    const float*  pow3 = (const float*)d_in[7];
    const float*  lam4 = (const float*)d_in[8];
    const float*  pow4 = (const float*)d_in[9];
    float* out = (float*)d_out;

    int B = in_sizes[0] / 4;  // x is (B, 4)
    hipMemsetAsync(out, 0, (size_t)B * sizeof(float), stream);

    dim3 block(256, 1, 1);
    dim3 grid((B + 255) / 256, 4, 1);   // 512 x 4 = 2048 blocks, 8 waves/SIMD
    nested_formula_r4<<<grid, block, 0, stream>>>(
        x, lam0, lam1, pow1, lam2, pow2, lam3, pow3, lam4, pow4, out, B);
}